// Round 1
// baseline (543.269 us; speedup 1.0000x reference)
//
#include <hip/hip_runtime.h>
#include <hip/hip_bf16.h>
#include <stdint.h>

// Problem constants (from reference)
#define M_DIM 8192              // 4*2048 batch*seq rows
#define N_DIM 4096              // out_features
#define K_DIM 4096              // in_features
#define NOG   4096              // num out groups (out_group=1)
#define NIG   512               // num in groups (in_group=8)

typedef __bf16 bf16;
typedef __attribute__((ext_vector_type(8))) __bf16 bf16x8;   // 4 VGPRs — MFMA A/B frag
typedef __attribute__((ext_vector_type(4))) float f32x4;     // MFMA C/D frag

// ---------------------------------------------------------------------------
// async global->LDS, 16 B per lane. LDS dest is wave-uniform base + lane*16.
__device__ __forceinline__ void gload16(const void* g, void* lds) {
    __builtin_amdgcn_global_load_lds(
        (__attribute__((address_space(1))) void*)g,
        (__attribute__((address_space(3))) void*)lds,
        16 /*size*/, 0 /*offset*/, 0 /*aux*/);
}

// ---------------------------------------------------------------------------
// Kernel 1: fp32 -> bf16 convert of the activation matrix. 8 elems/thread.
__global__ __launch_bounds__(256) void k_convert(const float* __restrict__ in,
                                                 bf16* __restrict__ out) {
    int i = blockIdx.x * blockDim.x + threadIdx.x;   // grid sized exactly
    const float4* p = (const float4*)in + (size_t)i * 2;
    float4 a = p[0], b = p[1];
    bf16x8 o;
    o[0] = (bf16)a.x; o[1] = (bf16)a.y; o[2] = (bf16)a.z; o[3] = (bf16)a.w;
    o[4] = (bf16)b.x; o[5] = (bf16)b.y; o[6] = (bf16)b.z; o[7] = (bf16)b.w;
    ((bf16x8*)out)[i] = o;
}

// ---------------------------------------------------------------------------
// Kernel 2: AQLM dequant. One thread per (out_feature o, in_group g):
//   W[o, g*8 .. g*8+7] = codebooks[codes[o,g]] * scales[o]   -> bf16
__global__ __launch_bounds__(256) void k_dequant(const int* __restrict__ codes,
                                                 const float* __restrict__ cb,
                                                 const float* __restrict__ scales,
                                                 bf16* __restrict__ w) {
    int i = blockIdx.x * blockDim.x + threadIdx.x;   // i = o*NIG + g, exact grid
    int o = i >> 9;                                   // NIG = 512
    unsigned code = (unsigned)codes[i];
    float s = scales[o];
    const float4* e = (const float4*)(cb + (size_t)code * 8);
    float4 e0 = e[0], e1 = e[1];
    bf16x8 v;
    v[0] = (bf16)(e0.x * s); v[1] = (bf16)(e0.y * s);
    v[2] = (bf16)(e0.z * s); v[3] = (bf16)(e0.w * s);
    v[4] = (bf16)(e1.x * s); v[5] = (bf16)(e1.y * s);
    v[6] = (bf16)(e1.z * s); v[7] = (bf16)(e1.w * s);
    ((bf16x8*)w)[i] = v;
}

// ---------------------------------------------------------------------------
// Kernel 3: C[m,n] = sum_k A[m,k]*B[n,k] + bias[n]   (B = dequantized W, NT gemm)
// m97 structure: 128x128 tile, BK=32, 256 threads = 4 waves in 2x2, each wave
// 4x4 of 16x16x32 MFMA tiles. global_load_lds width-16 staging, unpadded LDS.
#define BM 128
#define BN 128
#define BK 32
#define KSTEPS (K_DIM / BK)

__global__ __launch_bounds__(256) void k_gemm_bt_bias(
    const bf16* __restrict__ A,      // [M_DIM, K_DIM]
    const bf16* __restrict__ B,      // [N_DIM, K_DIM]
    const float* __restrict__ bias,  // [N_DIM]
    float* __restrict__ C)           // [M_DIM, N_DIM]
{
    __shared__ __align__(16) bf16 As[BM * BK];   // 8 KB
    __shared__ __align__(16) bf16 Bs[BN * BK];   // 8 KB

    const int tid  = threadIdx.x;
    const int wave = tid >> 6;         // 0..3
    const int lane = tid & 63;
    const int quad = lane >> 4;        // 0..3
    const int l16  = lane & 15;

    const int bm0 = blockIdx.y * BM;
    const int bn0 = blockIdx.x * BN;

    const int wm = (wave >> 1) * 64;   // wave's 64x64 subtile
    const int wn = (wave & 1) * 64;

    // Staging: wave `wave` fills rows [wave*32, wave*32+32) of As and Bs,
    // two issues of 16 rows each. Lane l -> row l>>2, col (l&3)*8 elems,
    // which is exactly LDS base + lane*16 bytes (row-major, 32 bf16/row).
    const int srow = lane >> 2;
    const int scol = (lane & 3) * 8;
    const bf16* Ag0 = A + (size_t)(bm0 + wave * 32 + srow) * K_DIM + scol;
    const bf16* Ag1 = Ag0 + (size_t)16 * K_DIM;
    const bf16* Bg0 = B + (size_t)(bn0 + wave * 32 + srow) * K_DIM + scol;
    const bf16* Bg1 = Bg0 + (size_t)16 * K_DIM;

    bf16* AsW = As + wave * 32 * BK;   // wave-uniform LDS bases
    bf16* BsW = Bs + wave * 32 * BK;

    f32x4 acc[4][4] = {};

    for (int ks = 0; ks < KSTEPS; ++ks) {
        gload16(Ag0, AsW);
        gload16(Ag1, AsW + 16 * BK);
        gload16(Bg0, BsW);
        gload16(Bg1, BsW + 16 * BK);
        Ag0 += BK; Ag1 += BK; Bg0 += BK; Bg1 += BK;
        __syncthreads();   // drains vmcnt -> staged data visible

        bf16x8 af[4], bfr[4];
        #pragma unroll
        for (int t = 0; t < 4; ++t) {
            // A frag: A[m = l16][k = quad*8 + j]; B frag mirrors with n = l16.
            af[t]  = *(const bf16x8*)(As + (wm + t * 16 + l16) * BK + quad * 8);
            bfr[t] = *(const bf16x8*)(Bs + (wn + t * 16 + l16) * BK + quad * 8);
        }
        #pragma unroll
        for (int i = 0; i < 4; ++i)
            #pragma unroll
            for (int j = 0; j < 4; ++j)
                acc[i][j] = __builtin_amdgcn_mfma_f32_16x16x32_bf16(
                    af[i], bfr[j], acc[i][j], 0, 0, 0);

        __syncthreads();   // all reads done before next overwrite
    }

    // Epilogue: C/D layout col = lane&15, row = quad*4 + reg  [m89/m91-verified]
    #pragma unroll
    for (int j = 0; j < 4; ++j) {
        const int gn = bn0 + wn + j * 16 + l16;
        const float bz = bias[gn];
        #pragma unroll
        for (int i = 0; i < 4; ++i) {
            float* cp = C + (size_t)(bm0 + wm + i * 16 + quad * 4) * N_DIM + gn;
            #pragma unroll
            for (int r = 0; r < 4; ++r)
                cp[(size_t)r * N_DIM] = acc[i][j][r] + bz;
        }
    }
}

// ---------------------------------------------------------------------------
extern "C" void kernel_launch(void* const* d_in, const int* in_sizes, int n_in,
                              void* d_out, int out_size, void* d_ws, size_t ws_size,
                              hipStream_t stream) {
    const float* input     = (const float*)d_in[0];   // [4,2048,4096]
    const int*   codes     = (const int*)d_in[1];     // [4096,512,1]
    const float* codebooks = (const float*)d_in[2];   // [1,65536,1,8]
    const float* scales    = (const float*)d_in[3];   // [4096]
    const float* bias      = (const float*)d_in[4];   // [4096]
    float* out = (float*)d_out;                        // [4,2048,4096]

    // Workspace: A_bf16 (67.1 MB) then W_bf16 (33.5 MB); both fully written
    // before the GEMM reads them, so the 0xAA poison is irrelevant.
    bf16* Abf = (bf16*)d_ws;
    bf16* Wbf = (bf16*)((char*)d_ws + (size_t)M_DIM * K_DIM * sizeof(bf16));

    (void)in_sizes; (void)n_in; (void)out_size; (void)ws_size;

    // 1) activation fp32 -> bf16  (8 elems/thread, exact grid)
    k_convert<<<(M_DIM * (size_t)K_DIM / 8) / 256, 256, 0, stream>>>(input, Abf);

    // 2) dequantize W -> bf16  (one thread per (o, g), exact grid)
    k_dequant<<<((size_t)NOG * NIG) / 256, 256, 0, stream>>>(codes, codebooks, scales, Wbf);

    // 3) NT GEMM + bias
    dim3 grid(N_DIM / BN, M_DIM / BM);   // (32, 64)
    k_gemm_bt_bias<<<grid, 256, 0, stream>>>(Abf, Wbf, bias, out);
}

// Round 2
// 514.587 us; speedup vs baseline: 1.0557x; 1.0557x over previous
//
#include <hip/hip_runtime.h>
#include <hip/hip_bf16.h>
#include <stdint.h>

// Problem constants (from reference)
#define M_DIM 8192              // 4*2048 batch*seq rows
#define N_DIM 4096              // out_features
#define K_DIM 4096              // in_features
#define NOG   4096              // num out groups (out_group=1)
#define NIG   512               // num in groups (in_group=8)

typedef __bf16 bf16;
typedef __attribute__((ext_vector_type(8))) __bf16 bf16x8;   // 4 VGPRs — MFMA A/B frag
typedef __attribute__((ext_vector_type(4))) __bf16 bf16x4;   // 8 B
typedef __attribute__((ext_vector_type(4))) float f32x4;     // MFMA C/D frag

// ---------------------------------------------------------------------------
// async global->LDS, 16 B per lane. LDS dest is wave-uniform base + lane*16.
__device__ __forceinline__ void gload16(const void* g, void* lds) {
    __builtin_amdgcn_global_load_lds(
        (__attribute__((address_space(1))) void*)g,
        (__attribute__((address_space(3))) void*)lds,
        16 /*size*/, 0 /*offset*/, 0 /*aux*/);
}

// ---------------------------------------------------------------------------
// Kernel 1: fp32 -> bf16 convert. Wave-contiguous float4 loads, bf16x4 stores.
__global__ __launch_bounds__(256) void k_convert(const float* __restrict__ in,
                                                 bf16* __restrict__ out) {
    int i0 = blockIdx.x * 512 + threadIdx.x;      // float4 index
    const float4* p = (const float4*)in;
    float4 a = p[i0], b = p[i0 + 256];
    bf16x4 oa, ob;
    oa[0] = (bf16)a.x; oa[1] = (bf16)a.y; oa[2] = (bf16)a.z; oa[3] = (bf16)a.w;
    ob[0] = (bf16)b.x; ob[1] = (bf16)b.y; ob[2] = (bf16)b.z; ob[3] = (bf16)b.w;
    ((bf16x4*)out)[i0]       = oa;
    ((bf16x4*)out)[i0 + 256] = ob;
}

// ---------------------------------------------------------------------------
// Kernel 2: AQLM dequant. One thread per (out_feature o, in_group g):
//   W[o, g*8 .. g*8+7] = codebooks[codes[o,g]] * scales[o]   -> bf16
__global__ __launch_bounds__(256) void k_dequant(const int* __restrict__ codes,
                                                 const float* __restrict__ cb,
                                                 const float* __restrict__ scales,
                                                 bf16* __restrict__ w) {
    int i = blockIdx.x * blockDim.x + threadIdx.x;   // i = o*NIG + g, exact grid
    int o = i >> 9;                                   // NIG = 512
    unsigned code = (unsigned)codes[i];
    float s = scales[o];
    const float4* e = (const float4*)(cb + (size_t)code * 8);
    float4 e0 = e[0], e1 = e[1];
    bf16x8 v;
    v[0] = (bf16)(e0.x * s); v[1] = (bf16)(e0.y * s);
    v[2] = (bf16)(e0.z * s); v[3] = (bf16)(e0.w * s);
    v[4] = (bf16)(e1.x * s); v[5] = (bf16)(e1.y * s);
    v[6] = (bf16)(e1.z * s); v[7] = (bf16)(e1.w * s);
    ((bf16x8*)w)[i] = v;
}

// ---------------------------------------------------------------------------
// Kernel 3: C[m,n] = sum_k A[m,k]*B[n,k] + bias[n]   (NT gemm, B = dequant W)
// Restructured vs m97: BM=256 x BN=128, 4 waves (2x2), WAVE tile 128x64 ->
// 42.7 FLOP/LDS-byte (vs 32 for 64x64 waves), 32 MFMA per barrier-pair.
// LDS layout XOR-swizzled at 16B granularity: staging lane l loads global
// (row l>>2, blk (l&3)^((l>>2)&3)), so reads hit 4 distinct bank spans
// instead of 2 (8-way -> 4-way conflict).
#define BM 256
#define BN 128
#define BK 32
#define KSTEPS (K_DIM / BK)

__global__ __launch_bounds__(256, 2) void k_gemm_bt_bias(
    const bf16* __restrict__ A,      // [M_DIM, K_DIM]
    const bf16* __restrict__ B,      // [N_DIM, K_DIM]
    const float* __restrict__ bias,  // [N_DIM]
    float* __restrict__ C)           // [M_DIM, N_DIM]
{
    __shared__ __align__(16) bf16 As[BM * BK];   // 16 KB
    __shared__ __align__(16) bf16 Bs[BN * BK];   //  8 KB

    const int tid  = threadIdx.x;
    const int wave = tid >> 6;         // 0..3
    const int lane = tid & 63;
    const int quad = lane >> 4;        // 0..3
    const int l16  = lane & 15;

    const int bm0 = blockIdx.y * BM;
    const int bn0 = blockIdx.x * BN;

    const int wm = (wave >> 1) * 128;  // wave's 128x64 subtile
    const int wn = (wave & 1) * 64;

    // Staging: within each 16-row chunk, lane l -> LDS offset l*16B
    //   = (row l>>2, 16B-blk l&3). Global source blk is XOR-swizzled.
    const int srow = lane >> 2;
    const int sblk = (lane & 3) ^ (srow & 3);     // global 16B block to fetch
    const int scol = sblk * 8;                     // bf16 elements

    // A: wave stages rows [wave*64, wave*64+64) in 4 issues of 16 rows.
    // B: wave stages rows [wave*32, wave*32+32) in 2 issues.
    const bf16* Ag = A + (size_t)(bm0 + wave * 64 + srow) * K_DIM + scol;
    const bf16* Bg = B + (size_t)(bn0 + wave * 32 + srow) * K_DIM + scol;
    bf16* AsW = As + wave * 64 * BK;   // wave-uniform LDS bases
    bf16* BsW = Bs + wave * 32 * BK;

    // De-swizzled read block: global blk q of row R lives at LDS blk q^(R&3);
    // R&3 == l16&3 for all our read rows (wm, wn, i*16 are multiples of 16).
    const int rblkA = (quad ^ (l16 & 3)) * 8;

    f32x4 acc[8][4] = {};

    const size_t rstep = (size_t)16 * K_DIM;

    for (int ks = 0; ks < KSTEPS; ++ks) {
        gload16(Ag,              AsW);
        gload16(Ag + rstep,      AsW + 16 * BK);
        gload16(Ag + 2 * rstep,  AsW + 32 * BK);
        gload16(Ag + 3 * rstep,  AsW + 48 * BK);
        gload16(Bg,              BsW);
        gload16(Bg + rstep,      BsW + 16 * BK);
        Ag += BK; Bg += BK;
        __syncthreads();   // drains vmcnt -> staged data visible

        bf16x8 af[8], bfr[4];
        #pragma unroll
        for (int t = 0; t < 8; ++t)
            af[t]  = *(const bf16x8*)(As + (wm + t * 16 + l16) * BK + rblkA);
        #pragma unroll
        for (int t = 0; t < 4; ++t)
            bfr[t] = *(const bf16x8*)(Bs + (wn + t * 16 + l16) * BK + rblkA);

        #pragma unroll
        for (int i = 0; i < 8; ++i)
            #pragma unroll
            for (int j = 0; j < 4; ++j)
                acc[i][j] = __builtin_amdgcn_mfma_f32_16x16x32_bf16(
                    af[i], bfr[j], acc[i][j], 0, 0, 0);

        __syncthreads();   // all reads done before next overwrite
    }

    // Epilogue: C/D layout col = lane&15, row = quad*4 + reg  [m89/m91-verified]
    #pragma unroll
    for (int j = 0; j < 4; ++j) {
        const int gn = bn0 + wn + j * 16 + l16;
        const float bz = bias[gn];
        #pragma unroll
        for (int i = 0; i < 8; ++i) {
            float* cp = C + (size_t)(bm0 + wm + i * 16 + quad * 4) * N_DIM + gn;
            #pragma unroll
            for (int r = 0; r < 4; ++r)
                cp[(size_t)r * N_DIM] = acc[i][j][r] + bz;
        }
    }
}

// ---------------------------------------------------------------------------
extern "C" void kernel_launch(void* const* d_in, const int* in_sizes, int n_in,
                              void* d_out, int out_size, void* d_ws, size_t ws_size,
                              hipStream_t stream) {
    const float* input     = (const float*)d_in[0];   // [4,2048,4096]
    const int*   codes     = (const int*)d_in[1];     // [4096,512,1]
    const float* codebooks = (const float*)d_in[2];   // [1,65536,1,8]
    const float* scales    = (const float*)d_in[3];   // [4096]
    const float* bias      = (const float*)d_in[4];   // [4096]
    float* out = (float*)d_out;                        // [4,2048,4096]

    // Workspace: A_bf16 (67.1 MB) then W_bf16 (33.5 MB); both fully written
    // before the GEMM reads them, so the 0xAA poison is irrelevant.
    bf16* Abf = (bf16*)d_ws;
    bf16* Wbf = (bf16*)((char*)d_ws + (size_t)M_DIM * K_DIM * sizeof(bf16));

    (void)in_sizes; (void)n_in; (void)out_size; (void)ws_size;

    // 1) activation fp32 -> bf16  (2 float4 / thread, exact grid)
    k_convert<<<(M_DIM * (size_t)K_DIM / 4) / 512, 256, 0, stream>>>(input, Abf);

    // 2) dequantize W -> bf16  (one thread per (o, g), exact grid)
    k_dequant<<<((size_t)NOG * NIG) / 256, 256, 0, stream>>>(codes, codebooks, scales, Wbf);

    // 3) NT GEMM + bias
    dim3 grid(N_DIM / BN, M_DIM / BM);   // (32, 32)
    k_gemm_bt_bias<<<grid, 256, 0, stream>>>(Abf, Wbf, bias, out);
}